// Round 10
// baseline (171.267 us; speedup 1.0000x reference)
//
#include <hip/hip_runtime.h>
#include <float.h>

#define B_   2
#define F_   8192
#define Q_   4096
#define NC   128         // F-chunks (= blocks contributing per point group)
#define FC   (F_/NC)     // 64 triangles per chunk -> 6-bit local index in key
#define PTS  256         // threads per block
#define PPT  4           // points per thread
#define NGRP 8           // point groups: (Q/(PTS*PPT)) * B = 4*2

typedef float f2 __attribute__((ext_vector_type(2)));
typedef float f4u __attribute__((ext_vector_type(4), aligned(4)));
typedef unsigned int uint;
typedef unsigned long long ull;

__device__ __forceinline__ f2 clamp01(f2 x) {
    f2 z = {0.f, 0.f}, o = {1.f, 1.f};
    return __builtin_elementwise_min(__builtin_elementwise_max(x, z), o);
}

// ---------------------------------------------------------------------------
// Exact reference-order Ericson barycentrics. Contract OFF: every op rounds
// exactly like the numpy reference; op order matches term-for-term.
// jnp.select first-true-wins priority; _safe_div(n,d) = n/(d==0?1:d).
__device__ __forceinline__ void bary_uvw(
    float ax, float ay, float az,
    float bx, float by, float bz,
    float cx, float cy, float cz,
    float px, float py, float pz,
    float& u, float& v, float& w)
{
#pragma clang fp contract(off)
    float abx = bx - ax, aby = by - ay, abz = bz - az;
    float acx = cx - ax, acy = cy - ay, acz = cz - az;
    float apx = px - ax, apy = py - ay, apz = pz - az;
    float d1 = abx*apx + aby*apy + abz*apz;
    float d2 = acx*apx + acy*apy + acz*apz;
    float bpx = px - bx, bpy = py - by, bpz = pz - bz;
    float d3 = abx*bpx + aby*bpy + abz*bpz;
    float d4 = acx*bpx + acy*bpy + acz*bpz;
    float qx = px - cx, qy = py - cy, qz = pz - cz;
    float d5 = abx*qx + aby*qy + abz*qz;
    float d6 = acx*qx + acy*qy + acz*qz;
    float vc = d1*d4 - d3*d2;
    float vb = d5*d2 - d1*d6;
    float va = d3*d6 - d5*d4;

    bool c1 = (d1 <= 0.f) && (d2 <= 0.f);
    bool c2 = (d3 >= 0.f) && (d4 <= d3);
    bool c3 = (vc <= 0.f) && (d1 >= 0.f) && (d3 <= 0.f);
    bool c4 = (d6 >= 0.f) && (d5 <= d6);
    bool c5 = (vb <= 0.f) && (d2 >= 0.f) && (d6 <= 0.f);
    bool c6 = (va <= 0.f) && (d4 >= d3) && (d5 >= d6);

    bool e1 = c1;
    bool p1 = !c1;
    bool e2 = p1 && c2;
    bool p2 = p1 && !c2;
    bool e3 = p2 && c3;
    bool p3 = p2 && !c3;
    bool e4 = p3 && c4;
    bool p4 = p3 && !c4;
    bool e5 = p4 && c5;
    bool p5 = p4 && !c5;
    bool e6 = p5 && c6;

    float d43 = d4 - d3;
    float d56 = d5 - d6;
    float n  = e3 ? d1        : (e5 ? d2        : (e6 ? d43         : 1.f));
    float dd = e3 ? (d1 - d3) : (e5 ? (d2 - d6) : (e6 ? (d43 + d56) : (va + vb + vc)));
    dd = (dd == 0.f) ? 1.f : dd;   // _safe_div
    float t = n / dd;

    float vi = vb * t;
    float wi = vc * t;
    u = e1 ? 1.f : (e2 ? 0.f : (e3 ? 1.f - t : (e4 ? 0.f : (e5 ? 1.f - t : (e6 ? 0.f     : 1.f - vi - wi)))));
    v = e1 ? 0.f : (e2 ? 1.f : (e3 ? t       : (e4 ? 0.f : (e5 ? 0.f     : (e6 ? 1.f - t : vi)))));
    w = e1 ? 0.f : (e2 ? 0.f : (e3 ? 0.f     : (e4 ? 1.f : (e5 ? t       : (e6 ? t       : wi)))));
}

// Cheap nomination distance^2, one point-pair vs one triangle.
__device__ __forceinline__ f2 pair_dist(
    f2 px, f2 py, f2 pz,
    float ax, float ay, float az,
    float abx, float aby, float abz,
    float acx, float acy, float acz,
    float daa, float dcc, float dac, float dbc, float kk,
    float rdaa, float rdcc, float rdbc, float rnn)
{
    f2 apx = px - ax, apy = py - ay, apz = pz - az;
    f2 d1  = abx*apx + aby*apy + abz*apz;
    f2 d2  = acx*apx + acy*apy + acz*apz;
    f2 app = apx*apx + apy*apy + apz*apz;

    f2 t1 = d1*dcc - d2*dac;
    f2 t2 = d2*daa - d1*dac;
    f2 t12n = 1.f - (t1 + t2)*rnn;
    f2 sgr  = (d1*t1 + d2*t2)*rnn;
    f2 ins  = __builtin_elementwise_min(__builtin_elementwise_min(t1, t2), t12n);

    f2 td1 = d1 + d1;
    f2 tab = clamp01(d1 * rdaa);
    f2 rab = tab*(td1 - tab*daa);
    f2 tac = clamp01(d2 * rdcc);
    f2 rac = tac*((d2 + d2) - tac*dcc);
    f2 d43 = (d2 - d1) + kk;
    f2 sbc = clamp01(d43 * rdbc);
    f2 rbc = (td1 - daa) + sbc*((d43 + d43) - sbc*dbc);
    f2 rmax = __builtin_elementwise_max(__builtin_elementwise_max(rab, rac), rbc);

    f2 red;
    red.x = (ins.x >= 0.f) ? sgr.x : rmax.x;
    red.y = (ins.y >= 0.f) ? sgr.y : rmax.y;
    f2 z = {0.f, 0.f};
    return __builtin_elementwise_max(app - red, z);   // clamp: neg would wrap key
}

// ---------------------------------------------------------------------------
// Fused single kernel. Phase 1: cheap loop nominates top-2/chunk (sortable
// keys). Phase 2: exact np-order re-eval of both nominees (raw coords from
// LDS; bit-identical inputs => bit-identical d^2), pack (d_bits<<32)|face
// (u64 min == lex-(d,face) min == jnp.argmin first-occurrence), atomicMin
// into key64[b][q]. Phase 3: last-done block per point group (atomic counter)
// coherently re-reads its own 1024 points' winners and runs the epilogue —
// no second kernel launch, no keys round-trip through a second dispatch.
// NO cheap-distance filtering anywhere (R5 lesson: sliver error tail).
__global__ __launch_bounds__(PTS, 4) void fused_kernel(
    const float* __restrict__ tri, const float* __restrict__ pts,
    const float* __restrict__ nrm, const float* __restrict__ cmp,
    const int* __restrict__ faces,
    ull* __restrict__ key64, uint* __restrict__ cnt,
    float* __restrict__ out)
{
    // per-tri 7 x float4 (112 B stride: gcd(28,32)=4 -> ~2-way on divergent
    // tail reads vs 4-way at stride 24): [0] a|daa [1] ab|dcc [2] ac|dac
    // [3] recips [4] b [5] c [6] pad
    __shared__ float4 S[FC * 7];
    __shared__ int s_last;
    const int tid = threadIdx.x;
    const int pb = blockIdx.x, cb = blockIdx.y, bb = blockIdx.z;

    if (tid < FC) {   // one thread stages one triangle fully
        const float* g = tri + ((size_t)bb * F_ + (size_t)cb * FC + tid) * 9;
        float ax = g[0], ay = g[1], az = g[2];
        float bx = g[3], by = g[4], bz = g[5];
        float cx = g[6], cy = g[7], cz = g[8];
        float abx = bx - ax, aby = by - ay, abz = bz - az;
        float acx = cx - ax, acy = cy - ay, acz = cz - az;
        float daa = abx*abx + aby*aby + abz*abz;
        float dcc = acx*acx + acy*acy + acz*acz;
        float dac = abx*acx + aby*acy + abz*acz;
        float dbc = daa + dcc - 2.f*dac;
        float nn  = daa*dcc - dac*dac;
        S[tid*7 + 0] = make_float4(ax, ay, az, daa);
        S[tid*7 + 1] = make_float4(abx, aby, abz, dcc);
        S[tid*7 + 2] = make_float4(acx, acy, acz, dac);
        S[tid*7 + 3] = make_float4(1.f/daa, 1.f/dcc, 1.f/dbc, 1.f/nn);
        S[tid*7 + 4] = make_float4(bx, by, bz, 0.f);
        S[tid*7 + 5] = make_float4(cx, cy, cz, 0.f);
    }
    __syncthreads();

    const int q0 = pb * (PTS * PPT) + tid * PPT;
    const float* p0 = pts + ((size_t)bb * Q_ + q0) * 3;
    f4u l0 = *(const f4u*)(p0);
    f4u l1 = *(const f4u*)(p0 + 4);
    f4u l2 = *(const f4u*)(p0 + 8);
    f2 pxA = {l0.x, l0.w}, pyA = {l0.y, l1.x}, pzA = {l0.z, l1.y};
    f2 pxB = {l1.z, l2.y}, pyB = {l1.w, l2.z}, pzB = {l2.x, l2.w};

    uint k00 = 0xFFFFFFFFu, k01 = 0xFFFFFFFFu;
    uint k10 = 0xFFFFFFFFu, k11 = 0xFFFFFFFFu;
    uint k20 = 0xFFFFFFFFu, k21 = 0xFFFFFFFFu;
    uint k30 = 0xFFFFFFFFu, k31 = 0xFFFFFFFFu;
    #pragma unroll 2
    for (int fl = 0; fl < FC; ++fl) {
        float4 c0 = S[fl*7 + 0];
        float4 c1 = S[fl*7 + 1];
        float4 c2 = S[fl*7 + 2];
        float4 c3 = S[fl*7 + 3];
        float daa = c0.w, dcc = c1.w, dac = c2.w;
        float dbc = daa + dcc - 2.f*dac;
        float kk  = daa - dac;

        f2 dA = pair_dist(pxA, pyA, pzA, c0.x, c0.y, c0.z,
                          c1.x, c1.y, c1.z, c2.x, c2.y, c2.z,
                          daa, dcc, dac, dbc, kk, c3.x, c3.y, c3.z, c3.w);
        f2 dB = pair_dist(pxB, pyB, pzB, c0.x, c0.y, c0.z,
                          c1.x, c1.y, c1.z, c2.x, c2.y, c2.z,
                          daa, dcc, dac, dbc, kk, c3.x, c3.y, c3.z, c3.w);

        uint kA0 = (__float_as_uint(dA.x) & 0xFFFFFFC0u) | (uint)fl;
        uint kA1 = (__float_as_uint(dA.y) & 0xFFFFFFC0u) | (uint)fl;
        uint kB0 = (__float_as_uint(dB.x) & 0xFFFFFFC0u) | (uint)fl;
        uint kB1 = (__float_as_uint(dB.y) & 0xFFFFFFC0u) | (uint)fl;
        uint lo, hi;
        lo = min(k00, kA0); hi = max(k00, kA0); k00 = lo; k01 = min(k01, hi);
        lo = min(k10, kA1); hi = max(k10, kA1); k10 = lo; k11 = min(k11, hi);
        lo = min(k20, kB0); hi = max(k20, kB0); k20 = lo; k21 = min(k21, hi);
        lo = min(k30, kB1); hi = max(k30, kB1); k30 = lo; k31 = min(k31, hi);
    }

    // Phase 2: exact np-order eval of both nominees per point -> atomicMin
    float pxs[4] = {l0.x, l0.w, l1.z, l2.y};
    float pys[4] = {l0.y, l1.x, l1.w, l2.z};
    float pzs[4] = {l0.z, l1.y, l2.x, l2.w};
    uint kk0[4] = {k00, k10, k20, k30};
    uint kk1[4] = {k01, k11, k21, k31};

    #pragma unroll
    for (int p = 0; p < 4; ++p) {
        float px = pxs[p], py = pys[p], pz = pzs[p];
        float dbest = FLT_MAX; int fbest = 0x7FFFFFFF;
        #pragma unroll
        for (int j = 0; j < 2; ++j) {
            int lf = (int)((j == 0 ? kk0[p] : kk1[p]) & 63u);
            float4 ra = S[lf*7 + 0];
            float4 rb = S[lf*7 + 4];
            float4 rc = S[lf*7 + 5];
            float u, v, w;
            bary_uvw(ra.x, ra.y, ra.z, rb.x, rb.y, rb.z, rc.x, rc.y, rc.z,
                     px, py, pz, u, v, w);
            float d2v;
            {
#pragma clang fp contract(off)
                float cpx = u*ra.x + v*rb.x + w*rc.x;
                float cpy = u*ra.y + v*rb.y + w*rc.y;
                float cpz = u*ra.z + v*rb.z + w*rc.z;
                float dx = cpx - px, dy = cpy - py, dz = cpz - pz;
                d2v = dx*dx + dy*dy + dz*dz;
            }
            int face = cb * FC + lf;
            if (d2v < dbest || (d2v == dbest && face < fbest)) { dbest = d2v; fbest = face; }
        }
        ull key = ((ull)__float_as_uint(dbest) << 32) | (uint)fbest;
        atomicMin(&key64[(size_t)bb * Q_ + q0 + p], key);
    }

    // Phase 3: last-done block of this point group runs the epilogue
    __threadfence();            // make this thread's atomics visible device-wide
    __syncthreads();            // all threads' atomics issued+fenced
    if (tid == 0) {
        uint old = atomicAdd(&cnt[bb * (Q_ / (PTS * PPT)) + pb], 1u);
        s_last = (old == (uint)(NC - 2)) ? 1 : 0;   // init 0xFFFFFFFF: olds are -1,0,..,NC-2
    }
    __syncthreads();
    if (!s_last) return;

    #pragma unroll
    for (int p = 0; p < 4; ++p) {
        const int t = bb * Q_ + q0 + p;
        float px = pxs[p], py = pys[p], pz = pzs[p];
        ull kv = atomicAdd(&key64[t], 0ULL);        // coherent read (L2s not x-coherent)
        const int bestf = (int)(kv & 0xFFFFFFFFull);

        const float* tg = tri + ((size_t)bb * F_ + bestf) * 9;
        const float* ng = nrm + ((size_t)bb * F_ + bestf) * 9;
        const float* cg = cmp + ((size_t)bb * F_ + bestf) * 9;
        f4u TA = *(const f4u*)(tg), TB = *(const f4u*)(tg + 4);
        float TC = tg[8];
        f4u NA = *(const f4u*)(ng), NB = *(const f4u*)(ng + 4);
        float NCs = ng[8];
        f4u CA = *(const f4u*)(cg), CB = *(const f4u*)(cg + 4);
        float CC = cg[8];

        float u, v, w;
        bary_uvw(TA.x, TA.y, TA.z, TA.w, TB.x, TB.y, TB.z, TB.w, TC,
                 px, py, pz, u, v, w);
        {
#pragma clang fp contract(off)
            u = fminf(fmaxf(u, 0.f), 1.f);
            v = fminf(fmaxf(v, 0.f), 1.f);
            w = fminf(fmaxf(w, 0.f), 1.f);

            float cpx = u * TA.x + v * TA.w + w * TB.z;
            float cpy = u * TA.y + v * TB.x + w * TB.w;
            float cpz = u * TA.z + v * TB.y + w * TC;
            float nx  = u * NA.x + v * NA.w + w * NB.z;
            float ny  = u * NA.y + v * NB.x + w * NB.w;
            float nz  = u * NA.z + v * NB.y + w * NCs;
            float mx  = u * CA.x + v * CA.w + w * CB.z;
            float my  = u * CA.y + v * CB.x + w * CB.w;
            float mz  = u * CA.z + v * CB.y + w * CC;

            const size_t S3 = (size_t)B_ * Q_ * 3;
            out[(size_t)t * 3 + 0] = cpx - px;
            out[(size_t)t * 3 + 1] = cpy - py;
            out[(size_t)t * 3 + 2] = cpz - pz;
            out[S3 + (size_t)t * 3 + 0] = nx;
            out[S3 + (size_t)t * 3 + 1] = ny;
            out[S3 + (size_t)t * 3 + 2] = nz;
            out[2 * S3 + (size_t)t * 3 + 0] = mx;
            out[2 * S3 + (size_t)t * 3 + 1] = my;
            out[2 * S3 + (size_t)t * 3 + 2] = mz;

            int k = 0; float mm = u;
            if (v > mm) { mm = v; k = 1; }
            if (w > mm) { k = 2; }
            out[3 * S3 + t] = (float)faces[((size_t)bb * F_ + bestf) * 3 + k];
        }
    }
}

extern "C" void kernel_launch(void* const* d_in, const int* in_sizes, int n_in,
                              void* d_out, int out_size, void* d_ws, size_t ws_size,
                              hipStream_t stream) {
    const float* tri   = (const float*)d_in[0];
    const float* pts   = (const float*)d_in[1];
    const float* nrm   = (const float*)d_in[2];
    const float* cmp   = (const float*)d_in[3];
    const int*   faces = (const int*)d_in[4];
    float* out = (float*)d_out;

    ull*  key64 = (ull*)d_ws;                                  // [B*Q] u64
    uint* cnt   = (uint*)((char*)d_ws + (size_t)B_ * Q_ * 8);  // [NGRP] u32

    // one memset covers both: keys -> u64 max (atomicMin identity),
    // counters -> 0xFFFFFFFF (= -1; last incrementer sees old == NC-2)
    hipMemsetAsync(d_ws, 0xFF, (size_t)B_ * Q_ * 8 + NGRP * 4, stream);

    dim3 g1(Q_ / (PTS * PPT), NC, B_);
    fused_kernel<<<g1, PTS, 0, stream>>>(tri, pts, nrm, cmp, faces, key64, cnt, out);
}

// Round 11
// 141.140 us; speedup vs baseline: 1.2135x; 1.2135x over previous
//
#include <hip/hip_runtime.h>
#include <float.h>

#define B_   2
#define F_   8192
#define Q_   4096
#define NC   128         // F-chunks; 2 exact pairs per finalize lane
#define FC   (F_/NC)     // 64 triangles per chunk -> 6-bit local index in key
#define PTS  256         // threads per scan block
#define PPT  4           // points per thread in scan

typedef float f2 __attribute__((ext_vector_type(2)));
typedef float f4u __attribute__((ext_vector_type(4), aligned(4)));
typedef unsigned int uint;

__device__ __forceinline__ f2 clamp01(f2 x) {
    f2 z = {0.f, 0.f}, o = {1.f, 1.f};
    return __builtin_elementwise_min(__builtin_elementwise_max(x, z), o);
}

// ---------------------------------------------------------------------------
// Exact reference-order Ericson barycentrics. Contract OFF: every op rounds
// exactly like the numpy reference; op order matches term-for-term.
// jnp.select first-true-wins priority; _safe_div(n,d) = n/(d==0?1:d).
__device__ __forceinline__ void bary_uvw(
    float ax, float ay, float az,
    float bx, float by, float bz,
    float cx, float cy, float cz,
    float px, float py, float pz,
    float& u, float& v, float& w)
{
#pragma clang fp contract(off)
    float abx = bx - ax, aby = by - ay, abz = bz - az;
    float acx = cx - ax, acy = cy - ay, acz = cz - az;
    float apx = px - ax, apy = py - ay, apz = pz - az;
    float d1 = abx*apx + aby*apy + abz*apz;
    float d2 = acx*apx + acy*apy + acz*apz;
    float bpx = px - bx, bpy = py - by, bpz = pz - bz;
    float d3 = abx*bpx + aby*bpy + abz*bpz;
    float d4 = acx*bpx + acy*bpy + acz*bpz;
    float qx = px - cx, qy = py - cy, qz = pz - cz;
    float d5 = abx*qx + aby*qy + abz*qz;
    float d6 = acx*qx + acy*qy + acz*qz;
    float vc = d1*d4 - d3*d2;
    float vb = d5*d2 - d1*d6;
    float va = d3*d6 - d5*d4;

    bool c1 = (d1 <= 0.f) && (d2 <= 0.f);
    bool c2 = (d3 >= 0.f) && (d4 <= d3);
    bool c3 = (vc <= 0.f) && (d1 >= 0.f) && (d3 <= 0.f);
    bool c4 = (d6 >= 0.f) && (d5 <= d6);
    bool c5 = (vb <= 0.f) && (d2 >= 0.f) && (d6 <= 0.f);
    bool c6 = (va <= 0.f) && (d4 >= d3) && (d5 >= d6);

    bool e1 = c1;
    bool p1 = !c1;
    bool e2 = p1 && c2;
    bool p2 = p1 && !c2;
    bool e3 = p2 && c3;
    bool p3 = p2 && !c3;
    bool e4 = p3 && c4;
    bool p4 = p3 && !c4;
    bool e5 = p4 && c5;
    bool p5 = p4 && !c5;
    bool e6 = p5 && c6;

    float d43 = d4 - d3;
    float d56 = d5 - d6;
    float n  = e3 ? d1        : (e5 ? d2        : (e6 ? d43         : 1.f));
    float dd = e3 ? (d1 - d3) : (e5 ? (d2 - d6) : (e6 ? (d43 + d56) : (va + vb + vc)));
    dd = (dd == 0.f) ? 1.f : dd;   // _safe_div
    float t = n / dd;

    float vi = vb * t;
    float wi = vc * t;
    u = e1 ? 1.f : (e2 ? 0.f : (e3 ? 1.f - t : (e4 ? 0.f : (e5 ? 1.f - t : (e6 ? 0.f     : 1.f - vi - wi)))));
    v = e1 ? 0.f : (e2 ? 1.f : (e3 ? t       : (e4 ? 0.f : (e5 ? 0.f     : (e6 ? 1.f - t : vi)))));
    w = e1 ? 0.f : (e2 ? 0.f : (e3 ? 0.f     : (e4 ? 1.f : (e5 ? t       : (e6 ? t       : wi)))));
}

// Cheap nomination distance^2, one point-pair vs one triangle.
__device__ __forceinline__ f2 pair_dist(
    f2 px, f2 py, f2 pz,
    float ax, float ay, float az,
    float abx, float aby, float abz,
    float acx, float acy, float acz,
    float daa, float dcc, float dac, float dbc, float kk,
    float rdaa, float rdcc, float rdbc, float rnn)
{
    f2 apx = px - ax, apy = py - ay, apz = pz - az;
    f2 d1  = abx*apx + aby*apy + abz*apz;
    f2 d2  = acx*apx + acy*apy + acz*apz;
    f2 app = apx*apx + apy*apy + apz*apz;

    f2 t1 = d1*dcc - d2*dac;
    f2 t2 = d2*daa - d1*dac;
    f2 t12n = 1.f - (t1 + t2)*rnn;
    f2 sgr  = (d1*t1 + d2*t2)*rnn;
    f2 ins  = __builtin_elementwise_min(__builtin_elementwise_min(t1, t2), t12n);

    f2 td1 = d1 + d1;
    f2 tab = clamp01(d1 * rdaa);
    f2 rab = tab*(td1 - tab*daa);
    f2 tac = clamp01(d2 * rdcc);
    f2 rac = tac*((d2 + d2) - tac*dcc);
    f2 d43 = (d2 - d1) + kk;
    f2 sbc = clamp01(d43 * rdbc);
    f2 rbc = (td1 - daa) + sbc*((d43 + d43) - sbc*dbc);
    f2 rmax = __builtin_elementwise_max(__builtin_elementwise_max(rab, rac), rbc);

    f2 red;
    red.x = (ins.x >= 0.f) ? sgr.x : rmax.x;
    red.y = (ins.y >= 0.f) ? sgr.y : rmax.y;
    f2 z = {0.f, 0.f};
    return __builtin_elementwise_max(app - red, z);   // clamp: neg would wrap key
}

// ---------------------------------------------------------------------------
// Scan (R9 structure): cheap loop nominates top-2/chunk (sortable uint keys);
// TAIL exact-evaluates both nominees per point with the np-order contract-off
// formula reading RAW a,b,c from LDS (bit-identical inputs => bit-identical
// d^2) and emits one (d_exact_bits, face) pair per (point, chunk).
// Stride-7 LDS records (112 B: gcd(28,32)=4 -> ~2-way on divergent tail reads
// vs 4-way at stride 24; R9->R10 measured conflicts 1.8M -> 1.07M).
// NO cheap-distance filtering anywhere (R5 lesson: sliver error tail).
__global__ __launch_bounds__(PTS, 4) void scan_kernel(
    const float* __restrict__ tri, const float* __restrict__ pts,
    uint2* __restrict__ keys)
{
    // [0] a|daa  [1] ab|dcc  [2] ac|dac  [3] recips  [4] b  [5] c  [6] pad
    __shared__ float4 S[FC * 7];
    const int tid = threadIdx.x;
    const int pb = blockIdx.x, cb = blockIdx.y, bb = blockIdx.z;

    if (tid < FC) {   // one thread stages one triangle fully
        const float* g = tri + ((size_t)bb * F_ + (size_t)cb * FC + tid) * 9;
        float ax = g[0], ay = g[1], az = g[2];
        float bx = g[3], by = g[4], bz = g[5];
        float cx = g[6], cy = g[7], cz = g[8];
        float abx = bx - ax, aby = by - ay, abz = bz - az;
        float acx = cx - ax, acy = cy - ay, acz = cz - az;
        float daa = abx*abx + aby*aby + abz*abz;
        float dcc = acx*acx + acy*acy + acz*acz;
        float dac = abx*acx + aby*acy + abz*acz;
        float dbc = daa + dcc - 2.f*dac;
        float nn  = daa*dcc - dac*dac;
        S[tid*7 + 0] = make_float4(ax, ay, az, daa);
        S[tid*7 + 1] = make_float4(abx, aby, abz, dcc);
        S[tid*7 + 2] = make_float4(acx, acy, acz, dac);
        S[tid*7 + 3] = make_float4(1.f/daa, 1.f/dcc, 1.f/dbc, 1.f/nn);
        S[tid*7 + 4] = make_float4(bx, by, bz, 0.f);
        S[tid*7 + 5] = make_float4(cx, cy, cz, 0.f);
    }
    __syncthreads();

    const int q0 = pb * (PTS * PPT) + tid * PPT;
    const float* p0 = pts + ((size_t)bb * Q_ + q0) * 3;
    f4u l0 = *(const f4u*)(p0);
    f4u l1 = *(const f4u*)(p0 + 4);
    f4u l2 = *(const f4u*)(p0 + 8);
    f2 pxA = {l0.x, l0.w}, pyA = {l0.y, l1.x}, pzA = {l0.z, l1.y};
    f2 pxB = {l1.z, l2.y}, pyB = {l1.w, l2.z}, pzB = {l2.x, l2.w};

    uint k00 = 0xFFFFFFFFu, k01 = 0xFFFFFFFFu;
    uint k10 = 0xFFFFFFFFu, k11 = 0xFFFFFFFFu;
    uint k20 = 0xFFFFFFFFu, k21 = 0xFFFFFFFFu;
    uint k30 = 0xFFFFFFFFu, k31 = 0xFFFFFFFFu;
    #pragma unroll 4
    for (int fl = 0; fl < FC; ++fl) {
        float4 c0 = S[fl*7 + 0];
        float4 c1 = S[fl*7 + 1];
        float4 c2 = S[fl*7 + 2];
        float4 c3 = S[fl*7 + 3];
        float daa = c0.w, dcc = c1.w, dac = c2.w;
        float dbc = daa + dcc - 2.f*dac;
        float kk  = daa - dac;

        f2 dA = pair_dist(pxA, pyA, pzA, c0.x, c0.y, c0.z,
                          c1.x, c1.y, c1.z, c2.x, c2.y, c2.z,
                          daa, dcc, dac, dbc, kk, c3.x, c3.y, c3.z, c3.w);
        f2 dB = pair_dist(pxB, pyB, pzB, c0.x, c0.y, c0.z,
                          c1.x, c1.y, c1.z, c2.x, c2.y, c2.z,
                          daa, dcc, dac, dbc, kk, c3.x, c3.y, c3.z, c3.w);

        uint kA0 = (__float_as_uint(dA.x) & 0xFFFFFFC0u) | (uint)fl;
        uint kA1 = (__float_as_uint(dA.y) & 0xFFFFFFC0u) | (uint)fl;
        uint kB0 = (__float_as_uint(dB.x) & 0xFFFFFFC0u) | (uint)fl;
        uint kB1 = (__float_as_uint(dB.y) & 0xFFFFFFC0u) | (uint)fl;
        uint lo, hi;
        lo = min(k00, kA0); hi = max(k00, kA0); k00 = lo; k01 = min(k01, hi);
        lo = min(k10, kA1); hi = max(k10, kA1); k10 = lo; k11 = min(k11, hi);
        lo = min(k20, kB0); hi = max(k20, kB0); k20 = lo; k21 = min(k21, hi);
        lo = min(k30, kB1); hi = max(k30, kB1); k30 = lo; k31 = min(k31, hi);
    }

    // TAIL: exact np-order eval of both nominees per point (raw coords from LDS)
    float pxs[4] = {l0.x, l0.w, l1.z, l2.y};
    float pys[4] = {l0.y, l1.x, l1.w, l2.z};
    float pzs[4] = {l0.z, l1.y, l2.x, l2.w};
    uint kk0[4] = {k00, k10, k20, k30};
    uint kk1[4] = {k01, k11, k21, k31};

    #pragma unroll
    for (int p = 0; p < 4; ++p) {
        float px = pxs[p], py = pys[p], pz = pzs[p];
        float dbest = FLT_MAX; int fbest = 0x7FFFFFFF;
        #pragma unroll
        for (int j = 0; j < 2; ++j) {
            int lf = (int)((j == 0 ? kk0[p] : kk1[p]) & 63u);
            float4 ra = S[lf*7 + 0];
            float4 rb = S[lf*7 + 4];
            float4 rc = S[lf*7 + 5];
            float u, v, w;
            bary_uvw(ra.x, ra.y, ra.z, rb.x, rb.y, rb.z, rc.x, rc.y, rc.z,
                     px, py, pz, u, v, w);
            float d2v;
            {
#pragma clang fp contract(off)
                float cpx = u*ra.x + v*rb.x + w*rc.x;
                float cpy = u*ra.y + v*rb.y + w*rc.y;
                float cpz = u*ra.z + v*rb.z + w*rc.z;
                float dx = cpx - px, dy = cpy - py, dz = cpz - pz;
                d2v = dx*dx + dy*dy + dz*dz;
            }
            int face = cb * FC + lf;
            if (d2v < dbest || (d2v == dbest && face < fbest)) { dbest = d2v; fbest = face; }
        }
        // point-major [b][q][chunk]: finalize reads coalesced uint4
        keys[((size_t)bb * Q_ + q0 + p) * NC + cb] = make_uint2(__float_as_uint(dbest), (uint)fbest);
    }
}

// ---------------------------------------------------------------------------
// Finalize: one WAVE per point; lane l loads chunks 2l,2l+1 exact pairs
// (coalesced uint4), wave lex-(d,face) reduce == jnp.argmin first occurrence.
// Lane 0 epilogue, contract-off np-order.
__global__ __launch_bounds__(256) void finalize_kernel(
    const float* __restrict__ tri, const float* __restrict__ pts,
    const float* __restrict__ nrm, const float* __restrict__ cmp,
    const int* __restrict__ faces,
    const uint2* __restrict__ keys,
    float* __restrict__ out)
{
#pragma clang fp contract(off)
    const int lane = threadIdx.x & 63;
    const int t = blockIdx.x * 4 + (threadIdx.x >> 6);
    const int bb = t >> 12;            // Q_ = 4096

    uint4 K = ((const uint4*)keys)[(size_t)t * (NC/2) + lane];
    float dbest = __uint_as_float(K.x); int fbest = (int)K.y;
    float d1v   = __uint_as_float(K.z); int f1v   = (int)K.w;
    if (d1v < dbest || (d1v == dbest && f1v < fbest)) { dbest = d1v; fbest = f1v; }
    for (int off = 32; off > 0; off >>= 1) {
        float od = __shfl_down(dbest, off);
        int   of = __shfl_down(fbest, off);
        if (od < dbest || (od == dbest && of < fbest)) { dbest = od; fbest = of; }
    }
    if (lane != 0) return;

    const float* pp = pts + (size_t)t * 3;
    float px = pp[0], py = pp[1], pz = pp[2];

    const int bestf = fbest;
    const float* tg = tri + ((size_t)bb * F_ + bestf) * 9;
    const float* ng = nrm + ((size_t)bb * F_ + bestf) * 9;
    const float* cg = cmp + ((size_t)bb * F_ + bestf) * 9;
    f4u TA = *(const f4u*)(tg), TB = *(const f4u*)(tg + 4);
    float TC = tg[8];
    f4u NA = *(const f4u*)(ng), NB = *(const f4u*)(ng + 4);
    float NCs = ng[8];
    f4u CA = *(const f4u*)(cg), CB = *(const f4u*)(cg + 4);
    float CC = cg[8];

    float u, v, w;
    bary_uvw(TA.x, TA.y, TA.z, TA.w, TB.x, TB.y, TB.z, TB.w, TC,
             px, py, pz, u, v, w);
    u = fminf(fmaxf(u, 0.f), 1.f);
    v = fminf(fmaxf(v, 0.f), 1.f);
    w = fminf(fmaxf(w, 0.f), 1.f);

    float cpx = u * TA.x + v * TA.w + w * TB.z;
    float cpy = u * TA.y + v * TB.x + w * TB.w;
    float cpz = u * TA.z + v * TB.y + w * TC;
    float nx  = u * NA.x + v * NA.w + w * NB.z;
    float ny  = u * NA.y + v * NB.x + w * NB.w;
    float nz  = u * NA.z + v * NB.y + w * NCs;
    float mx  = u * CA.x + v * CA.w + w * CB.z;
    float my  = u * CA.y + v * CB.x + w * CB.w;
    float mz  = u * CA.z + v * CB.y + w * CC;

    const size_t S3 = (size_t)B_ * Q_ * 3;
    out[(size_t)t * 3 + 0] = cpx - px;
    out[(size_t)t * 3 + 1] = cpy - py;
    out[(size_t)t * 3 + 2] = cpz - pz;
    out[S3 + (size_t)t * 3 + 0] = nx;
    out[S3 + (size_t)t * 3 + 1] = ny;
    out[S3 + (size_t)t * 3 + 2] = nz;
    out[2 * S3 + (size_t)t * 3 + 0] = mx;
    out[2 * S3 + (size_t)t * 3 + 1] = my;
    out[2 * S3 + (size_t)t * 3 + 2] = mz;

    int k = 0; float mm = u;
    if (v > mm) { mm = v; k = 1; }
    if (w > mm) { k = 2; }
    out[3 * S3 + t] = (float)faces[((size_t)bb * F_ + bestf) * 3 + k];
}

extern "C" void kernel_launch(void* const* d_in, const int* in_sizes, int n_in,
                              void* d_out, int out_size, void* d_ws, size_t ws_size,
                              hipStream_t stream) {
    const float* tri   = (const float*)d_in[0];
    const float* pts   = (const float*)d_in[1];
    const float* nrm   = (const float*)d_in[2];
    const float* cmp   = (const float*)d_in[3];
    const int*   faces = (const int*)d_in[4];
    float* out = (float*)d_out;

    uint2* keys = (uint2*)d_ws;   // [B][Q][NC] exact (d_bits, face) per chunk

    dim3 g1(Q_ / (PTS * PPT), NC, B_);
    scan_kernel<<<g1, PTS, 0, stream>>>(tri, pts, keys);
    finalize_kernel<<<(B_ * Q_) / 4, 256, 0, stream>>>(
        tri, pts, nrm, cmp, faces, keys, out);
}